// Round 4
// baseline (14287.201 us; speedup 1.0000x reference)
//
#include <hip/hip_runtime.h>
#include <stdint.h>

// One block per sample, fully fused, liveness-packed LDS pool of 9000 floats
// (36 KB) -> 4 blocks/CU (16 waves/CU). Key restructure vs v1:
//  - conv+semi_linear pairs fused (Z1, Z2 never materialized)
//  - wa-branch (X2 partial) computed right after T2 so T2 dies early
//  - wave-uniform LDS read addresses in all heavy loops (broadcast, no
//    bank conflicts), 10-20 accumulators per thread for ILP
// LDS layout (floats):
//  X1  [0,2250)    (25c,5h,18) s5..s7      T3 [0,1875) s8.5..s10 (over dead X1)
//  SX  [2250,2385) s1..s5(T90)
//  Z0A [2400,3075) s2..s3
//  Z0SL[3100,3550) (5c,5h,18) s3..s5
//  T90 [3552,3642) s4..s5
//  X2  [2250,6000) (125c,3h,10) s6.5..s9   (over dead stage-0 bufs)
//  T2  [6000,7250) (25c,5h,10) s6..s6.5
//  Z1S [6000,9000) (75c,4h,10) s7..s8      (over dead T2)
//  Z2S [6000,9000) (300c,2h,5) s9..s10     (over dead Z1S)

__global__ __launch_bounds__(256, 4)
void fused_net(const float* __restrict__ xg,
  const float* __restrict__ w0a_, const float* __restrict__ b0a_,
  const float* __restrict__ wl0_, const float* __restrict__ bl0_,
  const float* __restrict__ w0b_, const float* __restrict__ b0b_,
  const float* __restrict__ w0c_, const float* __restrict__ b0c_,
  const float* __restrict__ wr0_, const float* __restrict__ br0_,
  const float* __restrict__ w1_,  const float* __restrict__ b1_,
  const float* __restrict__ wl1_, const float* __restrict__ bl1_,
  const float* __restrict__ w2_,  const float* __restrict__ b2_,
  const float* __restrict__ wa_,  const float* __restrict__ ba_,
  const float* __restrict__ wra_, const float* __restrict__ bra_,
  const float* __restrict__ w0_,  const float* __restrict__ b0_,
  const float* __restrict__ wl2_, const float* __restrict__ bl2_,
  const float* __restrict__ w0b2_,const float* __restrict__ b0b2_,
  const float* __restrict__ w0c2_,const float* __restrict__ b0c2_,
  const float* __restrict__ wr02_,const float* __restrict__ br02_,
  float* __restrict__ outg)
{
  __shared__ float S[9000];
  const int tid = threadIdx.x;
  const int b = blockIdx.x;

  float* X1  = S + 0;     // stride 18
  float* T3  = S + 0;     // stride 5 (3 rows per ci -> ci*15)
  float* SX  = S + 2250;
  float* Z0A = S + 2400;
  float* Z0SL= S + 3100;  // stride 18
  float* T90 = S + 3552;
  float* X2  = S + 2250;  // stride 10 (3 rows per ci -> ci*30)
  float* T2  = S + 6000;  // stride 10 (5 rows per ci -> ci*50)
  float* Z1S = S + 6000;  // stride 10 (4 rows per ci -> ci*40)
  float* Z2S = S + 6000;  // stride 5  (2 rows per ci -> ci*10)

  // s1. load x (1,5,27)
  const float* xb = xg + (size_t)b * 135;
  for (int i = tid; i < 135; i += 256) SX[i] = xb[i];
  __syncthreads();

  // s2. z0a = conv w0a (1->5, kh=3, ph=1) : (5co,5h,27w)
  for (int i = tid; i < 675; i += 256) {
    int co = i / 135, r = i % 135, h = r / 27, w = r % 27;
    float acc = b0a_[co];
    #pragma unroll
    for (int dh = 0; dh < 3; ++dh) {
      int hi = h + dh - 1;
      if (hi >= 0 && hi < 5) acc += SX[hi*27 + w] * w0a_[co*3 + dh];
    }
    Z0A[i] = acc;
  }
  __syncthreads();

  // s3+s4 merged. Z0SL = relu(sl(Z0A, wl0)) [450]; T90 = sl(SX, wr0) [90]
  for (int i = tid; i < 540; i += 256) {
    if (i < 450) {
      int c = i / 90, r = i % 90, h = r / 18, o = r % 18;
      float acc = bl0_[o];
      const float* row = Z0A + (c*5 + h)*27;
      for (int w = 0; w < 27; ++w) acc += row[w] * wl0_[o*27 + w];
      Z0SL[(c*5 + h)*18 + o] = fmaxf(acc, 0.f);
    } else {
      int j = i - 450, h = j / 18, o = j % 18;
      float acc = br0_[o];
      const float* row = SX + h*27;
      for (int w = 0; w < 27; ++w) acc += row[w] * wr0_[o*27 + w];
      T90[h*18 + o] = acc;
    }
  }
  __syncthreads();

  // s5. X1 = conv w0b(Z0SL) + b0b + (w0c*T90 + b0c) : (25co,5h,18o)
  for (int i = tid; i < 2250; i += 256) {
    int co = i / 90, r = i % 90, h = r / 18, o = r % 18;
    float acc = b0b_[co] + b0c_[co] + T90[h*18 + o] * w0c_[co];
    #pragma unroll
    for (int dh = 0; dh < 3; ++dh) {
      int hi = h + dh - 1;
      if (hi >= 0 && hi < 5) {
        #pragma unroll
        for (int ci = 0; ci < 5; ++ci)
          acc += Z0SL[(ci*5 + hi)*18 + o] * w0b_[(co*5 + ci)*3 + dh];
      }
    }
    X1[i] = acc;   // i == (co*5+h)*18+o
  }
  __syncthreads();

  // s6. T2 = sl(X1, wra) : (25c,5h,10o)
  for (int i = tid; i < 1250; i += 256) {
    int c = i / 50, r = i % 50, h = r / 10, o = r % 10;
    float acc = bra_[o];
    const float* row = X1 + (c*5 + h)*18;
    for (int w = 0; w < 18; ++w) acc += row[w] * wra_[o*18 + w];
    T2[(c*5 + h)*10 + o] = acc;
  }
  __syncthreads();

  // s6.5. X2 = conv wa(T2) + b2 + ba : (125co,3h,10w)   (partial)
  for (int task = tid; task < 375; task += 256) {
    int co = task / 3, h = task % 3;
    float acc[10];
    float bias = b2_[co] + ba_[co];
    #pragma unroll
    for (int w = 0; w < 10; ++w) acc[w] = bias;
    for (int ci = 0; ci < 25; ++ci) {
      float wf0 = wa_[(co*25 + ci)*3 + 0];
      float wf1 = wa_[(co*25 + ci)*3 + 1];
      float wf2 = wa_[(co*25 + ci)*3 + 2];
      const float* r0 = T2 + ci*50 + h*10;
      #pragma unroll
      for (int w = 0; w < 10; ++w)
        acc[w] += r0[w]*wf0 + r0[10 + w]*wf1 + r0[20 + w]*wf2;
    }
    float* orow = X2 + (co*3 + h)*10;
    #pragma unroll
    for (int w = 0; w < 10; ++w) orow[w] = acc[w];
  }
  __syncthreads();

  // s7. Z1S = relu(sl(conv w1(X1), wl1)) fused : (75co,4h,10o), Z1 never stored
  for (int task = tid; task < 300; task += 256) {
    int co = task / 4, h = task % 4;
    float z1[18];
    float bias = b1_[co];
    #pragma unroll
    for (int w = 0; w < 18; ++w) z1[w] = bias;
    for (int ci = 0; ci < 25; ++ci) {
      float wx = w1_[(co*25 + ci)*2 + 0];
      float wy = w1_[(co*25 + ci)*2 + 1];
      const float* r0 = X1 + (ci*5 + h)*18;
      #pragma unroll
      for (int w = 0; w < 18; ++w) z1[w] += r0[w]*wx + r0[18 + w]*wy;
    }
    float* orow = Z1S + (co*4 + h)*10;
    #pragma unroll
    for (int o = 0; o < 10; ++o) {
      float acc = bl1_[o];
      #pragma unroll
      for (int w = 0; w < 18; ++w) acc += z1[w] * wl1_[o*18 + w];
      orow[o] = fmaxf(acc, 0.f);
    }
  }
  __syncthreads();

  // s8. X2 += conv w2(Z1S) : (125co,3h,10w)
  for (int task = tid; task < 375; task += 256) {
    int co = task / 3, h = task % 3;
    float* orow = X2 + (co*3 + h)*10;
    float acc[10];
    #pragma unroll
    for (int w = 0; w < 10; ++w) acc[w] = orow[w];
    for (int ci = 0; ci < 75; ++ci) {
      float wx = w2_[(co*75 + ci)*2 + 0];
      float wy = w2_[(co*75 + ci)*2 + 1];
      const float* r0 = Z1S + ci*40 + h*10;
      #pragma unroll
      for (int w = 0; w < 10; ++w) acc[w] += r0[w]*wx + r0[10 + w]*wy;
    }
    #pragma unroll
    for (int w = 0; w < 10; ++w) orow[w] = acc[w];
  }
  __syncthreads();

  // s8.5. T3 = sl(X2, wr02) : (125c,3h,5o)  (T3 overlays dead X1)
  for (int i = tid; i < 1875; i += 256) {
    int c = i / 15, r = i % 15, h = r / 5, o = r % 5;
    float acc = br02_[o];
    const float* row = X2 + (c*3 + h)*10;
    for (int w = 0; w < 10; ++w) acc += row[w] * wr02_[o*10 + w];
    T3[(c*3 + h)*5 + o] = acc;
  }
  __syncthreads();

  // s9. Z2S = relu(sl(conv w0(X2), wl2)) fused : (300co,2h,5o), Z2 never stored
  for (int co = tid; co < 300; co += 256) {
    float acc0[10], acc1[10];
    float bias = b0_[co];
    #pragma unroll
    for (int w = 0; w < 10; ++w) { acc0[w] = bias; acc1[w] = bias; }
    for (int ci = 0; ci < 125; ++ci) {
      float wx = w0_[(co*125 + ci)*2 + 0];
      float wy = w0_[(co*125 + ci)*2 + 1];
      const float* r0 = X2 + ci*30;   // rows h=0,1,2
      #pragma unroll
      for (int w = 0; w < 10; ++w) {
        float a0 = r0[w], a1 = r0[10 + w], a2 = r0[20 + w];
        acc0[w] += a0*wx + a1*wy;
        acc1[w] += a1*wx + a2*wy;
      }
    }
    float* orow = Z2S + co*10;   // (co*2+h2)*5+o
    #pragma unroll
    for (int o = 0; o < 5; ++o) {
      float s0 = bl2_[o], s1 = bl2_[o];
      #pragma unroll
      for (int w = 0; w < 10; ++w) {
        float wl = wl2_[o*10 + w];
        s0 += acc0[w] * wl;
        s1 += acc1[w] * wl;
      }
      orow[o]     = fmaxf(s0, 0.f);
      orow[5 + o] = fmaxf(s1, 0.f);
    }
  }
  __syncthreads();

  // s10. out = conv w0b2(Z2S) + conv w0c2(T3) : (512co,1,5w) -> global fp32
  float* ob = outg + (size_t)b * 2560;
  {
    const int co0 = tid, co1 = tid + 256;
    float acc[2][5];
    float bi0 = b0b2_[co0] + b0c2_[co0];
    float bi1 = b0b2_[co1] + b0c2_[co1];
    #pragma unroll
    for (int w = 0; w < 5; ++w) { acc[0][w] = bi0; acc[1][w] = bi1; }
    for (int ci = 0; ci < 300; ++ci) {          // w0b2: kh=2
      float w0x = w0b2_[(co0*300 + ci)*2 + 0];
      float w0y = w0b2_[(co0*300 + ci)*2 + 1];
      float w1x = w0b2_[(co1*300 + ci)*2 + 0];
      float w1y = w0b2_[(co1*300 + ci)*2 + 1];
      const float* r0 = Z2S + ci*10;
      #pragma unroll
      for (int w = 0; w < 5; ++w) {
        float a = r0[w], c2 = r0[5 + w];
        acc[0][w] += a*w0x + c2*w0y;
        acc[1][w] += a*w1x + c2*w1y;
      }
    }
    for (int ci = 0; ci < 125; ++ci) {          // w0c2: kh=3
      float u0 = w0c2_[(co0*125 + ci)*3 + 0];
      float u1 = w0c2_[(co0*125 + ci)*3 + 1];
      float u2 = w0c2_[(co0*125 + ci)*3 + 2];
      float v0 = w0c2_[(co1*125 + ci)*3 + 0];
      float v1 = w0c2_[(co1*125 + ci)*3 + 1];
      float v2 = w0c2_[(co1*125 + ci)*3 + 2];
      const float* r0 = T3 + ci*15;
      #pragma unroll
      for (int w = 0; w < 5; ++w) {
        float a = r0[w], c2 = r0[5 + w], e = r0[10 + w];
        acc[0][w] += a*u0 + c2*u1 + e*u2;
        acc[1][w] += a*v0 + c2*v1 + e*v2;
      }
    }
    #pragma unroll
    for (int w = 0; w < 5; ++w) {
      ob[co0*5 + w] = acc[0][w];
      ob[co1*5 + w] = acc[1][w];
    }
  }
}

extern "C" void kernel_launch(void* const* d_in, const int* in_sizes, int n_in,
                              void* d_out, int out_size, void* d_ws, size_t ws_size,
                              hipStream_t stream) {
  (void)in_sizes; (void)n_in; (void)d_ws; (void)ws_size;
  const float* p[31];
  for (int i = 0; i < 31; ++i) p[i] = (const float*)d_in[i];
  int B = out_size / 2560;   // (512*1*5) per sample
  fused_net<<<B, 256, 0, stream>>>(
      p[0],
      p[1],  p[2],  p[3],  p[4],  p[5],  p[6],  p[7],  p[8],  p[9],  p[10],
      p[11], p[12], p[13], p[14], p[15], p[16], p[17], p[18], p[19], p[20],
      p[21], p[22], p[23], p[24], p[25], p[26], p[27], p[28], p[29], p[30],
      (float*)d_out);
}

// Round 5
// 4022.018 us; speedup vs baseline: 3.5522x; 3.5522x over previous
//
#include <hip/hip_runtime.h>
#include <stdint.h>

// Two kernels per launch:
//  1) transpose_w: repack the 6 heavy weight matrices into [k][M] layout in
//     d_ws (2.42 MB) so compute lanes (lane=co) read dense consecutive lines.
//  2) fused_net: one block per sample, fully fused, 36 KB LDS pool,
//     __launch_bounds__(256,3) (~12 waves/CU). Heavy-layer weight reads go
//     through the transposed copies; activations are LDS broadcasts.
//
// d_ws float offsets: w1t@0 (75x50), wat@3750 (125x75), w2t@13125 (125x150),
// w0t@31875 (300x250), w0b2t@106875 (512x600), w0c2t@414075 (512x375),
// total 606075 floats = 2,424,300 B.

#define W1T_OFF   0
#define WAT_OFF   3750
#define W2T_OFF   13125
#define W0T_OFF   31875
#define WB2T_OFF  106875
#define WC2T_OFF  414075
#define WT_TOTAL  606075

__global__ __launch_bounds__(256)
void transpose_w(const float* __restrict__ w1, const float* __restrict__ wa,
                 const float* __restrict__ w2, const float* __restrict__ w0,
                 const float* __restrict__ wb2, const float* __restrict__ wc2,
                 float* __restrict__ ws) {
  int i = blockIdx.x * 256 + threadIdx.x;
  if (i < 3750) {                      // w1: M=75,  K=50
    int co = i / 50, k = i % 50;
    ws[W1T_OFF + k*75 + co] = w1[i];
  } else if (i < 13125) {              // wa: M=125, K=75
    int j = i - 3750; int co = j / 75, k = j % 75;
    ws[WAT_OFF + k*125 + co] = wa[j];
  } else if (i < 31875) {              // w2: M=125, K=150
    int j = i - 13125; int co = j / 150, k = j % 150;
    ws[W2T_OFF + k*125 + co] = w2[j];
  } else if (i < 106875) {             // w0: M=300, K=250
    int j = i - 31875; int co = j / 250, k = j % 250;
    ws[W0T_OFF + k*300 + co] = w0[j];
  } else if (i < 414075) {             // w0b2: M=512, K=600
    int j = i - 106875; int co = j / 600, k = j % 600;
    ws[WB2T_OFF + k*512 + co] = wb2[j];
  } else if (i < 606075) {             // w0c2: M=512, K=375
    int j = i - 414075; int co = j / 375, k = j % 375;
    ws[WC2T_OFF + k*512 + co] = wc2[j];
  }
}

// LDS layout (floats):
//  X1  [0,2250)    (25c,5h,18) s5..s7      T3 [0,1875) s8.5..s10 (over dead X1)
//  SX  [2250,2385) s1..s5
//  Z0A [2400,3075) s2..s3
//  Z0SL[3100,3550) s3..s5
//  T90 [3552,3642) s4..s5
//  X2  [2250,6000) (125c,3h,10) s6.5..s9
//  T2  [6000,7250) (25c,5h,10) s6..s6.5
//  Z1S [6000,9000) (75c,4h,10) s7..s8
//  Z2S [6000,9000) (300c,2h,5) s9..s10

__global__ __launch_bounds__(256, 3)
void fused_net(const float* __restrict__ xg,
  const float* __restrict__ w0a_, const float* __restrict__ b0a_,
  const float* __restrict__ wl0_, const float* __restrict__ bl0_,
  const float* __restrict__ w0b_, const float* __restrict__ b0b_,
  const float* __restrict__ w0c_, const float* __restrict__ b0c_,
  const float* __restrict__ wr0_, const float* __restrict__ br0_,
  const float* __restrict__ b1_,
  const float* __restrict__ wl1_, const float* __restrict__ bl1_,
  const float* __restrict__ b2_,
  const float* __restrict__ ba_,
  const float* __restrict__ wra_, const float* __restrict__ bra_,
  const float* __restrict__ b0_,
  const float* __restrict__ wl2_, const float* __restrict__ bl2_,
  const float* __restrict__ b0b2_,
  const float* __restrict__ b0c2_,
  const float* __restrict__ wr02_,const float* __restrict__ br02_,
  const float* __restrict__ w1t, const float* __restrict__ wat,
  const float* __restrict__ w2t, const float* __restrict__ w0t,
  const float* __restrict__ wb2t, const float* __restrict__ wc2t,
  float* __restrict__ outg)
{
  __shared__ float S[9000];
  const int tid = threadIdx.x;
  const int b = blockIdx.x;

  float* X1  = S + 0;     // stride 18
  float* T3  = S + 0;     // stride 5 (ci*15)
  float* SX  = S + 2250;
  float* Z0A = S + 2400;
  float* Z0SL= S + 3100;  // stride 18
  float* T90 = S + 3552;
  float* X2  = S + 2250;  // stride 10 (ci*30)
  float* T2  = S + 6000;  // stride 10 (ci*50)
  float* Z1S = S + 6000;  // stride 10 (ci*40)
  float* Z2S = S + 6000;  // stride 5  (ci*10)

  // s1. load x (1,5,27)
  const float* xb = xg + (size_t)b * 135;
  for (int i = tid; i < 135; i += 256) SX[i] = xb[i];
  __syncthreads();

  // s2. z0a = conv w0a (1->5, kh=3, ph=1) : (5co,5h,27w)
  for (int i = tid; i < 675; i += 256) {
    int co = i / 135, r = i % 135, h = r / 27, w = r % 27;
    float acc = b0a_[co];
    #pragma unroll
    for (int dh = 0; dh < 3; ++dh) {
      int hi = h + dh - 1;
      if (hi >= 0 && hi < 5) acc += SX[hi*27 + w] * w0a_[co*3 + dh];
    }
    Z0A[i] = acc;
  }
  __syncthreads();

  // s3+s4. Z0SL = relu(sl(Z0A, wl0)) [450]; T90 = sl(SX, wr0) [90]
  for (int i = tid; i < 540; i += 256) {
    if (i < 450) {
      int c = i / 90, r = i % 90, h = r / 18, o = r % 18;
      float acc = bl0_[o];
      const float* row = Z0A + (c*5 + h)*27;
      for (int w = 0; w < 27; ++w) acc += row[w] * wl0_[o*27 + w];
      Z0SL[(c*5 + h)*18 + o] = fmaxf(acc, 0.f);
    } else {
      int j = i - 450, h = j / 18, o = j % 18;
      float acc = br0_[o];
      const float* row = SX + h*27;
      for (int w = 0; w < 27; ++w) acc += row[w] * wr0_[o*27 + w];
      T90[h*18 + o] = acc;
    }
  }
  __syncthreads();

  // s5. X1 = conv w0b(Z0SL) + b0b + (w0c*T90 + b0c) : (25co,5h,18o)
  for (int i = tid; i < 2250; i += 256) {
    int co = i / 90, r = i % 90, h = r / 18, o = r % 18;
    float acc = b0b_[co] + b0c_[co] + T90[h*18 + o] * w0c_[co];
    #pragma unroll
    for (int dh = 0; dh < 3; ++dh) {
      int hi = h + dh - 1;
      if (hi >= 0 && hi < 5) {
        #pragma unroll
        for (int ci = 0; ci < 5; ++ci)
          acc += Z0SL[(ci*5 + hi)*18 + o] * w0b_[(co*5 + ci)*3 + dh];
      }
    }
    X1[i] = acc;
  }
  __syncthreads();

  // s6. T2 = sl(X1, wra) : (25c,5h,10o)
  for (int i = tid; i < 1250; i += 256) {
    int c = i / 50, r = i % 50, h = r / 10, o = r % 10;
    float acc = bra_[o];
    const float* row = X1 + (c*5 + h)*18;
    for (int w = 0; w < 18; ++w) acc += row[w] * wra_[o*18 + w];
    T2[(c*5 + h)*10 + o] = acc;
  }
  __syncthreads();

  // s6.5. X2 = conv wa(T2) + b2 + ba : (125co,3h,10w)  [transposed wat]
  for (int task = tid; task < 375; task += 256) {
    int co = task / 3, h = task % 3;
    float acc[10];
    float bias = b2_[co] + ba_[co];
    #pragma unroll
    for (int w = 0; w < 10; ++w) acc[w] = bias;
    for (int ci = 0; ci < 25; ++ci) {
      float wf0 = wat[(ci*3 + 0)*125 + co];
      float wf1 = wat[(ci*3 + 1)*125 + co];
      float wf2 = wat[(ci*3 + 2)*125 + co];
      const float* r0 = T2 + ci*50 + h*10;
      #pragma unroll
      for (int w = 0; w < 10; ++w)
        acc[w] += r0[w]*wf0 + r0[10 + w]*wf1 + r0[20 + w]*wf2;
    }
    float* orow = X2 + (co*3 + h)*10;
    #pragma unroll
    for (int w = 0; w < 10; ++w) orow[w] = acc[w];
  }
  __syncthreads();

  // s7. Z1S = relu(sl(conv w1(X1), wl1)) : (75co,4h,10o)  [transposed w1t]
  for (int task = tid; task < 300; task += 256) {
    int co = task / 4, h = task % 4;
    float z1[18];
    float bias = b1_[co];
    #pragma unroll
    for (int w = 0; w < 18; ++w) z1[w] = bias;
    for (int ci = 0; ci < 25; ++ci) {
      float wx = w1t[(ci*2 + 0)*75 + co];
      float wy = w1t[(ci*2 + 1)*75 + co];
      const float* r0 = X1 + (ci*5 + h)*18;
      #pragma unroll
      for (int w = 0; w < 18; ++w) z1[w] += r0[w]*wx + r0[18 + w]*wy;
    }
    float* orow = Z1S + (co*4 + h)*10;
    #pragma unroll
    for (int o = 0; o < 10; ++o) {
      float acc = bl1_[o];
      #pragma unroll
      for (int w = 0; w < 18; ++w) acc += z1[w] * wl1_[o*18 + w];
      orow[o] = fmaxf(acc, 0.f);
    }
  }
  __syncthreads();

  // s8. X2 += conv w2(Z1S) : (125co,3h,10w)  [transposed w2t]
  for (int task = tid; task < 375; task += 256) {
    int co = task / 3, h = task % 3;
    float* orow = X2 + (co*3 + h)*10;
    float acc[10];
    #pragma unroll
    for (int w = 0; w < 10; ++w) acc[w] = orow[w];
    for (int ci = 0; ci < 75; ++ci) {
      float wx = w2t[(ci*2 + 0)*125 + co];
      float wy = w2t[(ci*2 + 1)*125 + co];
      const float* r0 = Z1S + ci*40 + h*10;
      #pragma unroll
      for (int w = 0; w < 10; ++w) acc[w] += r0[w]*wx + r0[10 + w]*wy;
    }
    #pragma unroll
    for (int w = 0; w < 10; ++w) orow[w] = acc[w];
  }
  __syncthreads();

  // s8.5. T3 = sl(X2, wr02) : (125c,3h,5o)
  for (int i = tid; i < 1875; i += 256) {
    int c = i / 15, r = i % 15, h = r / 5, o = r % 5;
    float acc = br02_[o];
    const float* row = X2 + (c*3 + h)*10;
    for (int w = 0; w < 10; ++w) acc += row[w] * wr02_[o*10 + w];
    T3[(c*3 + h)*5 + o] = acc;
  }
  __syncthreads();

  // s9. Z2S = relu(sl(conv w0(X2), wl2)) : (300co,2h,5o)  [transposed w0t]
  for (int co = tid; co < 300; co += 256) {
    float acc0[10], acc1[10];
    float bias = b0_[co];
    #pragma unroll
    for (int w = 0; w < 10; ++w) { acc0[w] = bias; acc1[w] = bias; }
    for (int ci = 0; ci < 125; ++ci) {
      float wx = w0t[(ci*2 + 0)*300 + co];
      float wy = w0t[(ci*2 + 1)*300 + co];
      const float* r0 = X2 + ci*30;
      #pragma unroll
      for (int w = 0; w < 10; ++w) {
        float a0 = r0[w], a1 = r0[10 + w], a2 = r0[20 + w];
        acc0[w] += a0*wx + a1*wy;
        acc1[w] += a1*wx + a2*wy;
      }
    }
    float* orow = Z2S + co*10;
    #pragma unroll
    for (int o = 0; o < 5; ++o) {
      float s0 = bl2_[o], s1 = bl2_[o];
      #pragma unroll
      for (int w = 0; w < 10; ++w) {
        float wl = wl2_[o*10 + w];
        s0 += acc0[w] * wl;
        s1 += acc1[w] * wl;
      }
      orow[o]     = fmaxf(s0, 0.f);
      orow[5 + o] = fmaxf(s1, 0.f);
    }
  }
  __syncthreads();

  // s10. out = conv w0b2(Z2S) + conv w0c2(T3) : (512co,1,5w)
  //      thread handles co=tid and co=tid+256  [transposed wb2t/wc2t]
  float* ob = outg + (size_t)b * 2560;
  {
    const int co0 = tid, co1 = tid + 256;
    float acc[2][5];
    float bi0 = b0b2_[co0] + b0c2_[co0];
    float bi1 = b0b2_[co1] + b0c2_[co1];
    #pragma unroll
    for (int w = 0; w < 5; ++w) { acc[0][w] = bi0; acc[1][w] = bi1; }
    for (int ci = 0; ci < 300; ++ci) {          // w0b2: kh=2, K idx = ci*2+dh
      float w0x = wb2t[(ci*2 + 0)*512 + co0];
      float w0y = wb2t[(ci*2 + 1)*512 + co0];
      float w1x = wb2t[(ci*2 + 0)*512 + co1];
      float w1y = wb2t[(ci*2 + 1)*512 + co1];
      const float* r0 = Z2S + ci*10;
      #pragma unroll
      for (int w = 0; w < 5; ++w) {
        float a = r0[w], c2 = r0[5 + w];
        acc[0][w] += a*w0x + c2*w0y;
        acc[1][w] += a*w1x + c2*w1y;
      }
    }
    for (int ci = 0; ci < 125; ++ci) {          // w0c2: kh=3, K idx = ci*3+dh
      float u0 = wc2t[(ci*3 + 0)*512 + co0];
      float u1 = wc2t[(ci*3 + 1)*512 + co0];
      float u2 = wc2t[(ci*3 + 2)*512 + co0];
      float v0 = wc2t[(ci*3 + 0)*512 + co1];
      float v1 = wc2t[(ci*3 + 1)*512 + co1];
      float v2 = wc2t[(ci*3 + 2)*512 + co1];
      const float* r0 = T3 + ci*15;
      #pragma unroll
      for (int w = 0; w < 5; ++w) {
        float a = r0[w], c2 = r0[5 + w], e = r0[10 + w];
        acc[0][w] += a*u0 + c2*u1 + e*u2;
        acc[1][w] += a*v0 + c2*v1 + e*v2;
      }
    }
    #pragma unroll
    for (int w = 0; w < 5; ++w) {
      ob[co0*5 + w] = acc[0][w];
      ob[co1*5 + w] = acc[1][w];
    }
  }
}

extern "C" void kernel_launch(void* const* d_in, const int* in_sizes, int n_in,
                              void* d_out, int out_size, void* d_ws, size_t ws_size,
                              hipStream_t stream) {
  (void)in_sizes; (void)n_in; (void)ws_size;
  const float* p[31];
  for (int i = 0; i < 31; ++i) p[i] = (const float*)d_in[i];
  float* ws = (float*)d_ws;

  // 1) transpose heavy weights into d_ws
  transpose_w<<<(WT_TOTAL + 255) / 256, 256, 0, stream>>>(
      p[11] /*w1*/, p[17] /*wa*/, p[15] /*w2*/, p[21] /*w0*/,
      p[25] /*w0b2*/, p[27] /*w0c2*/, ws);

  // 2) fused net
  int B = out_size / 2560;
  fused_net<<<B, 256, 0, stream>>>(
      p[0],
      p[1],  p[2],  p[3],  p[4],  p[5],  p[6],  p[7],  p[8],  p[9],  p[10],
      p[12],                 // b1
      p[13], p[14],          // wl1, bl1
      p[16],                 // b2
      p[18],                 // ba
      p[19], p[20],          // wra, bra
      p[22],                 // b0
      p[23], p[24],          // wl2, bl2
      p[26],                 // b0b2
      p[28],                 // b0c2
      p[29], p[30],          // wr02, br02
      ws + W1T_OFF, ws + WAT_OFF, ws + W2T_OFF, ws + W0T_OFF,
      ws + WB2T_OFF, ws + WC2T_OFF,
      (float*)d_out);
}